// Round 4
// baseline (75.986 us; speedup 1.0000x reference)
//
#include <hip/hip_runtime.h>
#include <hip/hip_bf16.h>

#define NUM_TOKENS 262144
#define NUM_EXPERTS 128
#define TOPK 8

typedef unsigned long long u64;
typedef unsigned int u32;
typedef float __attribute__((ext_vector_type(4))) f32x4;
typedef float __attribute__((ext_vector_type(2))) f32x2;

// Compare-exchange: keep larger key in a. Keys unique -> no stability needed.
// Compiles to v_cmp_lt_u64 + 4 v_cndmask.
__device__ __forceinline__ void ce(u64& a, u64& b) {
    bool sw = b > a;
    u64 hi = sw ? b : a;
    u64 lo = sw ? a : b;
    a = hi; b = lo;
}

// Batcher odd-even mergesort, 8 elements, descending (19 CEs).
__device__ __forceinline__ void sort8(u64 k[8]) {
    ce(k[0],k[1]); ce(k[2],k[3]); ce(k[4],k[5]); ce(k[6],k[7]);
    ce(k[0],k[2]); ce(k[1],k[3]); ce(k[4],k[6]); ce(k[5],k[7]);
    ce(k[1],k[2]); ce(k[5],k[6]);
    ce(k[0],k[4]); ce(k[1],k[5]); ce(k[2],k[6]); ce(k[3],k[7]);
    ce(k[2],k[4]); ce(k[3],k[5]);
    ce(k[1],k[2]); ce(k[3],k[4]); ce(k[5],k[6]);
}

// Bitonic merge of a bitonic 8-seq -> sorted descending (12 CEs).
__device__ __forceinline__ void bmerge8(u64 k[8]) {
    ce(k[0],k[4]); ce(k[1],k[5]); ce(k[2],k[6]); ce(k[3],k[7]);
    ce(k[0],k[2]); ce(k[1],k[3]); ce(k[4],k[6]); ce(k[5],k[7]);
    ce(k[0],k[1]); ce(k[2],k[3]); ce(k[4],k[5]); ce(k[6],k[7]);
}

// Monotone fp32 -> u32; key = (sortable << 32) | (127 - idx). Unique keys;
// larger key == larger value, ties -> smaller expert index (lax.top_k order).
__device__ __forceinline__ u64 make_key(float v, u32 low) {
    u32 b = __float_as_uint(v);
    u32 hi = b ^ (0x80000000u | (u32)((int)b >> 31));
    return ((u64)hi << 32) | low;
}

// 4 lanes/token, 32 experts (2x 64B lines) per lane. Block = 64 tokens.
__global__ __launch_bounds__(256, 6) void select_topk_kernel(
    const float* __restrict__ logits, float* __restrict__ out)
{
    const int tid = blockIdx.x * 256 + threadIdx.x;
    const int t = tid >> 2;
    const int s = tid & 3;

    // Issue all 8 loads up-front; offsets 0..112B fold into load immediates.
    const f32x4* p = reinterpret_cast<const f32x4*>(
        logits + (size_t)t * NUM_EXPERTS + s * 32);
    f32x4 c0 = __builtin_nontemporal_load(p + 0);
    f32x4 c1 = __builtin_nontemporal_load(p + 1);
    f32x4 c2 = __builtin_nontemporal_load(p + 2);
    f32x4 c3 = __builtin_nontemporal_load(p + 3);
    f32x4 c4 = __builtin_nontemporal_load(p + 4);
    f32x4 c5 = __builtin_nontemporal_load(p + 5);
    f32x4 c6 = __builtin_nontemporal_load(p + 6);
    f32x4 c7 = __builtin_nontemporal_load(p + 7);

    const u32 lowb = 127u - (u32)(s * 32);

    u64 A[8];
    u64 kb[8];
    auto keys8 = [&](u64 k[8], f32x4 a, f32x4 b, u32 off) {
        k[0] = make_key(a[0], lowb - off);
        k[1] = make_key(a[1], lowb - off - 1);
        k[2] = make_key(a[2], lowb - off - 2);
        k[3] = make_key(a[3], lowb - off - 3);
        k[4] = make_key(b[0], lowb - off - 4);
        k[5] = make_key(b[1], lowb - off - 5);
        k[6] = make_key(b[2], lowb - off - 6);
        k[7] = make_key(b[3], lowb - off - 7);
    };
    auto merge_in = [&]() {  // A = sorted top-8 of (A ∪ kb), in place
#pragma unroll
        for (int i = 0; i < 8; ++i) {
            u64 b = kb[7 - i];
            A[i] = A[i] > b ? A[i] : b;
        }
        bmerge8(A);
    };

    keys8(A, c0, c1, 0);  sort8(A);
    keys8(kb, c2, c3, 8);  sort8(kb); merge_in();
    keys8(kb, c4, c5, 16); sort8(kb); merge_in();
    keys8(kb, c6, c7, 24); sort8(kb); merge_in();

    // Cross-lane merge across 4 sublanes; afterwards all 4 hold the same
    // global sorted top-8. xor masks 1,2 stay within the token group.
#pragma unroll
    for (int d = 1; d <= 2; d <<= 1) {
        u64 B[8];
#pragma unroll
        for (int i = 0; i < 8; ++i) B[i] = __shfl_xor(A[7 - i], d);
#pragma unroll
        for (int i = 0; i < 8; ++i) A[i] = A[i] > B[i] ? A[i] : B[i];
        bmerge8(A);
    }

    // Decode; softmax over selected 8 logits == renormalized top-k probs.
    float e[8];
    e[0] = 1.0f;
    float Z = 1.0f;
    const u32 hi0 = (u32)(A[0] >> 32);
    const float mx = __uint_as_float(hi0 ^ (0x80000000u | ~((u32)((int)hi0 >> 31))));
#pragma unroll
    for (int k = 1; k < 8; ++k) {
        u32 hi = (u32)(A[k] >> 32);
        float v = __uint_as_float(hi ^ (0x80000000u | ~((u32)((int)hi >> 31))));
        e[k] = __expf(v - mx);
        Z += e[k];
    }
    const float inv = 1.0f / Z;

    // Sublane s stores ranks 2s, 2s+1 (static cndmask tree).
    const bool s1 = (s & 1) != 0, s2 = (s & 2) != 0;
    u32 lA = s2 ? (s1 ? (u32)A[6] : (u32)A[4]) : (s1 ? (u32)A[2] : (u32)A[0]);
    u32 lB = s2 ? (s1 ? (u32)A[7] : (u32)A[5]) : (s1 ? (u32)A[3] : (u32)A[1]);
    float eA = s2 ? (s1 ? e[6] : e[4]) : (s1 ? e[2] : e[0]);
    float eB = s2 ? (s1 ? e[7] : e[5]) : (s1 ? e[3] : e[1]);

    f32x2 sid = { (float)(int)(127u - lA), (float)(int)(127u - lB) };
    f32x2 sw  = { eA * inv, eB * inv };

    __builtin_nontemporal_store(sid,
        reinterpret_cast<f32x2*>(out) + (size_t)t * 4 + s);
    __builtin_nontemporal_store(sw,
        reinterpret_cast<f32x2*>(out + (size_t)NUM_TOKENS * TOPK) + (size_t)t * 4 + s);
}

extern "C" void kernel_launch(void* const* d_in, const int* in_sizes, int n_in,
                              void* d_out, int out_size, void* d_ws, size_t ws_size,
                              hipStream_t stream) {
    const float* logits = (const float*)d_in[0];
    float* out = (float*)d_out;
    select_topk_kernel<<<NUM_TOKENS / 64, 256, 0, stream>>>(logits, out);
}